// Round 17
// baseline (99.024 us; speedup 1.0000x reference)
//
#include <hip/hip_runtime.h>
#include <hip/hip_bf16.h>
#include <math.h>

#define B_ 16384
#define NP 6
#define BLKP 172    // blocks per p
#define GRID (NP * BLKP)

typedef short v8s __attribute__((ext_vector_type(8)));
typedef short v4s __attribute__((ext_vector_type(4)));
typedef float v4f __attribute__((ext_vector_type(4)));

__device__ __forceinline__ float gelu_f(float x) {
    return 0.5f * x * (1.0f + erff(x * 0.7071067811865476f));
}
__device__ __forceinline__ unsigned short f2bf(float f) {
    union { float f; unsigned u; } x; x.f = f;
    unsigned r = x.u + 0x7FFFu + ((x.u >> 16) & 1u);
    return (unsigned short)(r >> 16);
}
__device__ __forceinline__ short bfs(float f) {   // HW RTNE cvt
    union { __hip_bfloat16 h; unsigned short u; } cv;
    cv.h = __float2bfloat16(f);
    return (short)cv.u;
}

// ---------------- kernel 1: fused {counts+lists+bitmap} and {weights->bf16 fragment-major} ----------------
// blocks 0..47: mask compaction; blocks 48..559: weight conversion
__global__ __launch_bounds__(256) void k_pre(
    const int* __restrict__ mask, int* __restrict__ counts,
    int* __restrict__ lists, unsigned long long* __restrict__ nb,
    const float* __restrict__ hw1, const float* __restrict__ gw1,
    const float* __restrict__ hw2, const float* __restrict__ hw3,
    unsigned short* __restrict__ w1f, unsigned short* __restrict__ w2f,
    unsigned short* __restrict__ w3f)
{
    int t = threadIdx.x;
    if (blockIdx.x < 48) {
        int p   = blockIdx.x >> 3;
        int seg = blockIdx.x & 7;
        int src = p >> 1;                        // 0,0,1,1,2,2
        int tgt = (0x102021 >> (p * 4)) & 0xF;   // 1,2,0,2,0,1
        int lane = t & 63;
        for (int it = 0; it < 8; ++it) {
            int b = seg * 2048 + it * 256 + t;
            int needs = (mask[b * 3 + src] != 0) && (mask[b * 3 + tgt] == 0);
            unsigned long long bal = __ballot(needs);
            int total = __popcll(bal);
            int base = 0;
            if (lane == 0) {
                nb[p * 256 + (b >> 6)] = bal;
                if (total) base = atomicAdd(&counts[p], total);
            }
            base = __shfl(base, 0, 64);
            if (needs) {
                int prefix = __popcll(bal & ((1ull << lane) - 1ull));
                lists[p * B_ + base + prefix] = b;
            }
        }
        return;
    }
    const int T1 = NP * 65536, T2 = NP * 9216, T3 = NP * 49152;
    for (int i = (blockIdx.x - 48) * 256 + t; i < T1 + T2 + T3; i += 512 * 256) {
        if (i < T1) {
            // w1f: ((p*128 + f)*64 + q*4 + g)*8 + j ; f = kt*8+n ; k = kt*32+g*8+j ; col = n*16+q
            int p = i >> 16, rem = i & 65535;
            int f = rem >> 9, within = rem & 511;
            int qg = within >> 3, j = within & 7;
            int q = qg >> 2, g = qg & 3;
            int kt = f >> 3, n = f & 7;
            int k = kt * 32 + g * 8 + j;
            int col = n * 16 + q;
            float v = (col < 96) ? hw1[p * 49152 + k * 96 + col] : gw1[p * 16384 + k * 32 + (col - 96)];
            w1f[i] = f2bf(v);
        } else if (i < T1 + T2) {
            // w2f: ((p*18 + f)*64 + q*4 + g)*8 + j ; f = n*3+kit
            int j2 = i - T1, p = j2 / 9216, rem = j2 % 9216;
            int f = rem >> 9, within = rem & 511;
            int qg = within >> 3, j = within & 7;
            int q = qg >> 2, g = qg & 3;
            int k = (f % 3) * 32 + g * 8 + j;
            int col = (f / 3) * 16 + q;
            w2f[j2] = f2bf(hw2[p * 9216 + k * 96 + col]);
        } else {
            // w3f: ((p*96 + f)*64 + q*4 + g)*8 + j ; f = (pc*8+n)*3+kit
            int j3 = i - T1 - T2, p = j3 / 49152, rem = j3 % 49152;
            int f = rem >> 9, within = rem & 511;
            int qg = within >> 3, j = within & 7;
            int q = qg >> 2, g = qg & 3;
            int k = (f % 3) * 32 + g * 8 + j;
            int col = (f / 3) * 16 + q;
            w3f[j3] = f2bf(hw3[p * 49152 + k * 512 + col]);
        }
    }
}

// ---------------- kernel 2: barrier-free all-L2 MFMA MLP + burst zero-fill ----------------
// 1032 blocks x 256 threads (4 waves). ~4 blocks/CU resident, 16 waves/CU.
__global__ __launch_bounds__(256) void k_main(
    const float* __restrict__ mus, const float* __restrict__ logvars,
    const unsigned short* __restrict__ w1f, const unsigned short* __restrict__ w2f,
    const unsigned short* __restrict__ w3f,
    const float* __restrict__ hb1, const float* __restrict__ hg1, const float* __restrict__ hbe1,
    const float* __restrict__ hb2, const float* __restrict__ hg2, const float* __restrict__ hbe2,
    const float* __restrict__ hb3,
    const float* __restrict__ gb1, const float* __restrict__ gg1, const float* __restrict__ gbe1,
    const float* __restrict__ gw2, const float* __restrict__ gb2,
    const int* __restrict__ counts, const int* __restrict__ lists,
    const unsigned long long* __restrict__ nb,
    float* __restrict__ out0, float* __restrict__ out1, float* __restrict__ out2)
{
    int cb = blockIdx.x;                 // 0..1031
    int p  = cb % 6, blk = cb / 6;       // blk 0..171
    int t  = threadIdx.x;                // 0..255
    int w  = t >> 6, l = t & 63, g = l >> 4, q = l & 15;
    int cnt = counts[p];

    __shared__ __align__(16) unsigned short smX[4 * 1664];     // 13312 B, per-wave [16][104]

    // -------- zero-fill setup: 96 rows/block, 24/wave; bitmap word in register --------
    int zr0  = blk * 96 + w * 24;
    int zn   = max(0, min(zr0 + 24, B_) - zr0);
    int wi0  = zr0 >> 6;
    unsigned long long zw0 = 0ull, zw1 = 0ull;
    if (zn > 0) {
        zw0 = nb[p * 256 + wi0];
        zw1 = nb[p * 256 + ((zr0 + zn - 1) >> 6)];
    }
    auto zburst = [&](int i0, int i1) {
        i1 = min(i1, zn);
        float4 z = make_float4(0.f, 0.f, 0.f, 0.f);
        for (int i = i0; i < i1; ++i) {
            int zr = zr0 + i;
            unsigned long long wd = ((zr >> 6) == wi0) ? zw0 : zw1;
            if (!((wd >> (zr & 63)) & 1ull)) {
                size_t rb = ((size_t)p * B_ + zr) * 256 + l * 4;
                *(float4*)(out0 + rb) = z;
                *(float4*)(out1 + rb) = z;
                if (l == 0) out2[p * B_ + zr] = 0.f;
            }
        }
    };

    int start = (blk * 4 + w) * 16;
    bool active = start < cnt;
    int nr = active ? min(16, cnt - start) : 0;
    int myrow = active ? lists[p * B_ + min(start + q, cnt - 1)] : 0;
    const float* Ab = mus     + (size_t)(p >> 1) * B_ * 256 + (size_t)myrow * 256 + g * 8;
    const float* Lb = logvars + (size_t)(p >> 1) * B_ * 256 + (size_t)myrow * 256 + g * 8;

    const unsigned short* w1p = w1f + (size_t)p * 65536;
    const unsigned short* w2p = w2f + (size_t)p * 9216;
    const unsigned short* w3p = w3f + (size_t)p * 49152;
    unsigned short* mX = smX + w * 1664;
    float gb2p = gb2[p];
    int fo = q * 32 + g * 8;

    // -------- issue all 8 mus-chunk loads first (critical path), then zero burst 0 --------
    float4 ma[8], mb[8];
    if (active) {
#pragma unroll
        for (int k = 0; k < 8; ++k) {
            ma[k] = *(const float4*)(Ab + k * 32);
            mb[k] = *(const float4*)(Ab + k * 32 + 4);
        }
    }
    zburst(0, 6);

    if (active) {
        // ============ phase 1: acc1[8], K=512, W1 fragments direct from L2 ============
        v4f acc1[8];
#pragma unroll
        for (int n = 0; n < 8; ++n) acc1[n] = (v4f){0.f, 0.f, 0.f, 0.f};

        float4 la[8], lb[8];
#pragma unroll
        for (int kt = 0; kt < 8; ++kt) {
            // issue logvars chunk kt (consumed in second half)
            la[kt] = *(const float4*)(Lb + kt * 32);
            lb[kt] = *(const float4*)(Lb + kt * 32 + 4);
            v8s a;
            a[0] = bfs(ma[kt].x); a[1] = bfs(ma[kt].y); a[2] = bfs(ma[kt].z); a[3] = bfs(ma[kt].w);
            a[4] = bfs(mb[kt].x); a[5] = bfs(mb[kt].y); a[6] = bfs(mb[kt].z); a[7] = bfs(mb[kt].w);
#pragma unroll
            for (int n = 0; n < 8; ++n) {
                v8s b = *(const v8s*)(w1p + (kt * 8 + n) * 512 + fo);
                acc1[n] = __builtin_amdgcn_mfma_f32_16x16x32_bf16(b, a, acc1[n], 0, 0, 0);
            }
        }
        zburst(6, 12);   // drain overlaps logvars-half MFMAs
#pragma unroll
        for (int kt = 0; kt < 8; ++kt) {
            v8s a;
            a[0] = bfs(la[kt].x); a[1] = bfs(la[kt].y); a[2] = bfs(la[kt].z); a[3] = bfs(la[kt].w);
            a[4] = bfs(lb[kt].x); a[5] = bfs(lb[kt].y); a[6] = bfs(lb[kt].z); a[7] = bfs(lb[kt].w);
#pragma unroll
            for (int n = 0; n < 8; ++n) {
                v8s b = *(const v8s*)(w1p + ((kt + 8) * 8 + n) * 512 + fo);
                acc1[n] = __builtin_amdgcn_mfma_f32_16x16x32_bf16(b, a, acc1[n], 0, 0, 0);
            }
        }

        // ====== LN1 + gelu; lane (g,q) holds row q, cols {n*16+4g+j} ======
        {
            float vb[8][4];
#pragma unroll
            for (int n = 0; n < 8; ++n) {
                float4 bb = (n < 6) ? *(const float4*)(hb1 + p * 96 + n * 16 + 4 * g)
                                    : *(const float4*)(gb1 + p * 32 + (n - 6) * 16 + 4 * g);
                vb[n][0] = acc1[n][0] + bb.x; vb[n][1] = acc1[n][1] + bb.y;
                vb[n][2] = acc1[n][2] + bb.z; vb[n][3] = acc1[n][3] + bb.w;
            }
            float hs = 0.f;
#pragma unroll
            for (int n = 0; n < 6; ++n)
#pragma unroll
                for (int j = 0; j < 4; ++j) hs += vb[n][j];
            hs += __shfl_xor(hs, 16, 64); hs += __shfl_xor(hs, 32, 64);
            float mean = hs * (1.f / 96.f);
            float sq = 0.f;
#pragma unroll
            for (int n = 0; n < 6; ++n)
#pragma unroll
                for (int j = 0; j < 4; ++j) { float d = vb[n][j] - mean; sq += d * d; }
            sq += __shfl_xor(sq, 16, 64); sq += __shfl_xor(sq, 32, 64);
            float rs = rsqrtf(sq * (1.f / 96.f) + 1e-5f);
#pragma unroll
            for (int n = 0; n < 6; ++n) {
                float4 ga = *(const float4*)(hg1  + p * 96 + n * 16 + 4 * g);
                float4 be = *(const float4*)(hbe1 + p * 96 + n * 16 + 4 * g);
                v4s xo;
                xo[0] = bfs(gelu_f((vb[n][0] - mean) * rs * ga.x + be.x));
                xo[1] = bfs(gelu_f((vb[n][1] - mean) * rs * ga.y + be.y));
                xo[2] = bfs(gelu_f((vb[n][2] - mean) * rs * ga.z + be.z));
                xo[3] = bfs(gelu_f((vb[n][3] - mean) * rs * ga.w + be.w));
                *(v4s*)(mX + q * 104 + n * 16 + 4 * g) = xo;
            }
            // gate branch (cols 96..127 = frags n=6,7)
            float gs = 0.f;
#pragma unroll
            for (int n = 6; n < 8; ++n)
#pragma unroll
                for (int j = 0; j < 4; ++j) gs += vb[n][j];
            gs += __shfl_xor(gs, 16, 64); gs += __shfl_xor(gs, 32, 64);
            float mg = gs * (1.f / 32.f);
            float gq = 0.f;
#pragma unroll
            for (int n = 6; n < 8; ++n)
#pragma unroll
                for (int j = 0; j < 4; ++j) { float d = vb[n][j] - mg; gq += d * d; }
            gq += __shfl_xor(gq, 16, 64); gq += __shfl_xor(gq, 32, 64);
            float rg = rsqrtf(gq * (1.f / 32.f) + 1e-5f);
            float gv = 0.f;
#pragma unroll
            for (int n = 6; n < 8; ++n) {
                int cg = (n - 6) * 16 + 4 * g;
                float4 ga = *(const float4*)(gg1  + p * 32 + cg);
                float4 be = *(const float4*)(gbe1 + p * 32 + cg);
                float4 w2 = *(const float4*)(gw2  + p * 32 + cg);
                gv += gelu_f((vb[n][0] - mg) * rg * ga.x + be.x) * w2.x;
                gv += gelu_f((vb[n][1] - mg) * rg * ga.y + be.y) * w2.y;
                gv += gelu_f((vb[n][2] - mg) * rg * ga.z + be.z) * w2.z;
                gv += gelu_f((vb[n][3] - mg) * rg * ga.w + be.w) * w2.w;
            }
            gv += __shfl_xor(gv, 16, 64); gv += __shfl_xor(gv, 32, 64);
            if (g == 0 && q < nr)
                out2[p * B_ + myrow] = 1.f / (1.f + expf(-(gv + gb2p)));
        }
        __builtin_amdgcn_s_waitcnt(0);   // lgkm: mX visible to this wave (wave-private slice)

        // ============ phase 2: X1 @ W2 (fragment-major, contiguous 1KB loads) ============
        {
            v4f acc2[6];
#pragma unroll
            for (int n = 0; n < 6; ++n) acc2[n] = (v4f){0.f, 0.f, 0.f, 0.f};
#pragma unroll
            for (int kit = 0; kit < 3; ++kit) {
                v8s xa = *(const v8s*)(mX + q * 104 + kit * 32 + g * 8);
#pragma unroll
                for (int n = 0; n < 6; ++n) {
                    v8s wb = *(const v8s*)(w2p + (n * 3 + kit) * 512 + fo);
                    acc2[n] = __builtin_amdgcn_mfma_f32_16x16x32_bf16(wb, xa, acc2[n], 0, 0, 0);
                }
            }
            // LN2 + gelu -> X2 (same buffer)
            float vc[6][4];
#pragma unroll
            for (int n = 0; n < 6; ++n) {
                float4 bb = *(const float4*)(hb2 + p * 96 + n * 16 + 4 * g);
                vc[n][0] = acc2[n][0] + bb.x; vc[n][1] = acc2[n][1] + bb.y;
                vc[n][2] = acc2[n][2] + bb.z; vc[n][3] = acc2[n][3] + bb.w;
            }
            float hs = 0.f;
#pragma unroll
            for (int n = 0; n < 6; ++n)
#pragma unroll
                for (int j = 0; j < 4; ++j) hs += vc[n][j];
            hs += __shfl_xor(hs, 16, 64); hs += __shfl_xor(hs, 32, 64);
            float mean = hs * (1.f / 96.f);
            float sq = 0.f;
#pragma unroll
            for (int n = 0; n < 6; ++n)
#pragma unroll
                for (int j = 0; j < 4; ++j) { float d = vc[n][j] - mean; sq += d * d; }
            sq += __shfl_xor(sq, 16, 64); sq += __shfl_xor(sq, 32, 64);
            float rs = rsqrtf(sq * (1.f / 96.f) + 1e-5f);
#pragma unroll
            for (int n = 0; n < 6; ++n) {
                float4 ga = *(const float4*)(hg2  + p * 96 + n * 16 + 4 * g);
                float4 be = *(const float4*)(hbe2 + p * 96 + n * 16 + 4 * g);
                v4s xo;
                xo[0] = bfs(gelu_f((vc[n][0] - mean) * rs * ga.x + be.x));
                xo[1] = bfs(gelu_f((vc[n][1] - mean) * rs * ga.y + be.y));
                xo[2] = bfs(gelu_f((vc[n][2] - mean) * rs * ga.z + be.z));
                xo[3] = bfs(gelu_f((vc[n][3] - mean) * rs * ga.w + be.w));
                *(v4s*)(mX + q * 104 + n * 16 + 4 * g) = xo;
            }
        }
        __builtin_amdgcn_s_waitcnt(0);
        zburst(12, 18);   // drain overlaps phase 3

        // ============ phase 3: X2 @ W3 (fragment-major), float4 stores (live rows only) ============
        {
            size_t base = ((size_t)(p * B_ + myrow)) * 256;
#pragma unroll 1
            for (int pc = 0; pc < 4; ++pc) {
                v4f acc3[8];
#pragma unroll
                for (int n = 0; n < 8; ++n) acc3[n] = (v4f){0.f, 0.f, 0.f, 0.f};
#pragma unroll
                for (int kit = 0; kit < 3; ++kit) {
                    v8s xa = *(const v8s*)(mX + q * 104 + kit * 32 + g * 8);
#pragma unroll
                    for (int n = 0; n < 8; ++n) {
                        v8s wb = *(const v8s*)(w3p + ((pc * 8 + n) * 3 + kit) * 512 + fo);
                        acc3[n] = __builtin_amdgcn_mfma_f32_16x16x32_bf16(wb, xa, acc3[n], 0, 0, 0);
                    }
                }
#pragma unroll
                for (int n = 0; n < 8; ++n) {
                    int c = pc * 128 + n * 16 + 4 * g;
                    float4 bb = *(const float4*)(hb3 + p * 512 + c);
                    if (q < nr) {
                        float o0 = acc3[n][0] + bb.x, o1 = acc3[n][1] + bb.y;
                        float o2 = acc3[n][2] + bb.z, o3 = acc3[n][3] + bb.w;
                        if (pc < 2) {
                            *(float4*)(out0 + base + c) = make_float4(o0, o1, o2, o3);
                        } else {
                            o0 = fminf(fmaxf(o0, -6.f), 2.f); o1 = fminf(fmaxf(o1, -6.f), 2.f);
                            o2 = fminf(fmaxf(o2, -6.f), 2.f); o3 = fminf(fmaxf(o3, -6.f), 2.f);
                            *(float4*)(out1 + base + c - 256) = make_float4(o0, o1, o2, o3);
                        }
                    }
                }
            }
        }
        zburst(18, 24);
    } else {
        // inactive wave: finish remaining zero rows immediately (pure writer)
        zburst(6, 24);
    }
}

extern "C" void kernel_launch(void* const* d_in, const int* in_sizes, int n_in,
                              void* d_out, int out_size, void* d_ws, size_t ws_size,
                              hipStream_t stream)
{
    (void)in_sizes; (void)n_in; (void)out_size; (void)ws_size;

    const float* mus     = (const float*)d_in[0];
    const float* logvars = (const float*)d_in[1];
    const int*   mask    = (const int*)d_in[2];   // numpy bool -> int32 per harness
    const float* hw1  = (const float*)d_in[3];
    const float* hb1  = (const float*)d_in[4];
    const float* hg1  = (const float*)d_in[5];
    const float* hbe1 = (const float*)d_in[6];
    const float* hw2  = (const float*)d_in[7];
    const float* hb2  = (const float*)d_in[8];
    const float* hg2  = (const float*)d_in[9];
    const float* hbe2 = (const float*)d_in[10];
    const float* hw3  = (const float*)d_in[11];
    const float* hb3  = (const float*)d_in[12];
    const float* gw1  = (const float*)d_in[13];
    const float* gb1  = (const float*)d_in[14];
    const float* gg1  = (const float*)d_in[15];
    const float* gbe1 = (const float*)d_in[16];
    const float* gw2  = (const float*)d_in[17];
    const float* gb2  = (const float*)d_in[18];

    float* out0 = (float*)d_out;
    float* out1 = out0 + (size_t)NP * B_ * 256;
    float* out2 = out1 + (size_t)NP * B_ * 256;

    int* counts = (int*)d_ws;                                    // 16 ints
    int* lists  = counts + 16;                                   // NP*B_ ints
    unsigned short* w1f = (unsigned short*)(lists + NP * B_);    // NP*65536
    unsigned short* w2f = w1f + (size_t)NP * 65536;              // NP*9216
    unsigned short* w3f = w2f + (size_t)NP * 9216;               // NP*49152
    unsigned long long* nbm = (unsigned long long*)(w3f + (size_t)NP * 49152);  // NP*256

    hipMemsetAsync(d_ws, 0, 64, stream);
    k_pre<<<dim3(560), dim3(256), 0, stream>>>(
        mask, counts, lists, nbm, hw1, gw1, hw2, hw3, w1f, w2f, w3f);
    k_main<<<dim3(GRID), dim3(256), 0, stream>>>(
        mus, logvars, w1f, w2f, w3f,
        hb1, hg1, hbe1, hb2, hg2, hbe2, hb3,
        gb1, gg1, gbe1, gw2, gb2,
        counts, lists, nbm, out0, out1, out2);
}

// Round 18
// 94.642 us; speedup vs baseline: 1.0463x; 1.0463x over previous
//
#include <hip/hip_runtime.h>
#include <hip/hip_bf16.h>
#include <math.h>

#define B_ 16384
#define NP 6

typedef short v8s __attribute__((ext_vector_type(8)));
typedef short v4s __attribute__((ext_vector_type(4)));
typedef float v4f __attribute__((ext_vector_type(4)));

__device__ __forceinline__ float gelu_f(float x) {
    return 0.5f * x * (1.0f + erff(x * 0.7071067811865476f));
}
__device__ __forceinline__ unsigned short f2bf(float f) {
    union { float f; unsigned u; } x; x.f = f;
    unsigned r = x.u + 0x7FFFu + ((x.u >> 16) & 1u);
    return (unsigned short)(r >> 16);
}
__device__ __forceinline__ short bfs(float f) {   // HW RTNE cvt
    union { __hip_bfloat16 h; unsigned short u; } cv;
    cv.h = __float2bfloat16(f);
    return (short)cv.u;
}

// ---------------- kernel 1: fused {counts+lists+bitmap} and {weights->bf16 repack} ----------------
// blocks 0..47: mask compaction; blocks 48..559: weight conversion
__global__ __launch_bounds__(256) void k_pre(
    const int* __restrict__ mask, int* __restrict__ counts,
    int* __restrict__ lists, unsigned long long* __restrict__ nb,
    const float* __restrict__ hw1, const float* __restrict__ gw1,
    const float* __restrict__ hw2, const float* __restrict__ hw3,
    unsigned short* __restrict__ w1t, unsigned short* __restrict__ w2f,
    unsigned short* __restrict__ w3f)
{
    int t = threadIdx.x;
    if (blockIdx.x < 48) {
        int p   = blockIdx.x >> 3;
        int seg = blockIdx.x & 7;
        int src = p >> 1;                        // 0,0,1,1,2,2
        int tgt = (0x102021 >> (p * 4)) & 0xF;   // 1,2,0,2,0,1
        int lane = t & 63;
        for (int it = 0; it < 8; ++it) {
            int b = seg * 2048 + it * 256 + t;
            int needs = (mask[b * 3 + src] != 0) && (mask[b * 3 + tgt] == 0);
            unsigned long long bal = __ballot(needs);
            int total = __popcll(bal);
            int base = 0;
            if (lane == 0) {
                nb[p * 256 + (b >> 6)] = bal;
                if (total) base = atomicAdd(&counts[p], total);
            }
            base = __shfl(base, 0, 64);
            if (needs) {
                int prefix = __popcll(bal & ((1ull << lane) - 1ull));
                lists[p * B_ + base + prefix] = b;
            }
        }
        return;
    }
    const int T1 = NP * 65536, T2 = NP * 9216, T3 = NP * 49152;
    for (int i = (blockIdx.x - 48) * 256 + t; i < T1 + T2 + T3; i += 512 * 256) {
        if (i < T1) {
            int p = i >> 16, rem = i & 65535, c = rem >> 9, k = rem & 511;
            float v = (c < 96) ? hw1[p * 49152 + k * 96 + c] : gw1[p * 16384 + k * 32 + (c - 96)];
            w1t[i] = f2bf(v);
        } else if (i < T1 + T2) {
            // w2f: ((p*18 + f)*64 + q*4 + g)*8 + j ; f = n*3+kit
            int j2 = i - T1, p = j2 / 9216, rem = j2 % 9216;
            int f = rem >> 9, within = rem & 511;
            int qg = within >> 3, j = within & 7;
            int q = qg >> 2, g = qg & 3;
            int k = (f % 3) * 32 + g * 8 + j;
            int col = (f / 3) * 16 + q;
            w2f[j2] = f2bf(hw2[p * 9216 + k * 96 + col]);
        } else {
            // w3f: ((p*96 + f)*64 + q*4 + g)*8 + j ; f = (pc*8+n)*3+kit
            int j3 = i - T1 - T2, p = j3 / 49152, rem = j3 % 49152;
            int f = rem >> 9, within = rem & 511;
            int qg = within >> 3, j = within & 7;
            int q = qg >> 2, g = qg & 3;
            int k = (f % 3) * 32 + g * 8 + j;
            int col = (f / 3) * 16 + q;
            w3f[j3] = f2bf(hw3[p * 49152 + k * 512 + col]);
        }
    }
}

// ---------------- kernel 2: fine-burst zero-fill + persistent W1-in-LDS MFMA MLP ----------------
// 256 blocks x 512 threads (8 waves). One block per CU.
__global__ __launch_bounds__(512, 2) void k_main(
    const float* __restrict__ mus, const float* __restrict__ logvars,
    const unsigned short* __restrict__ w1t, const unsigned short* __restrict__ w2f,
    const unsigned short* __restrict__ w3f,
    const float* __restrict__ hb1, const float* __restrict__ hg1, const float* __restrict__ hbe1,
    const float* __restrict__ hb2, const float* __restrict__ hg2, const float* __restrict__ hbe2,
    const float* __restrict__ hb3,
    const float* __restrict__ gb1, const float* __restrict__ gg1, const float* __restrict__ gbe1,
    const float* __restrict__ gw2, const float* __restrict__ gb2,
    const int* __restrict__ counts, const int* __restrict__ lists,
    const unsigned long long* __restrict__ nb,
    float* __restrict__ out0, float* __restrict__ out1, float* __restrict__ out2)
{
    int cb = blockIdx.x;                 // 0..255
    int p  = cb % 6, blk = cb / 6;       // p<4: blk 0..42 ; p>=4: blk 0..41
    int t  = threadIdx.x;
    int w  = t >> 6, l = t & 63, g = l >> 4, q = l & 15;
    int cnt = counts[p];

    __shared__ __align__(16) unsigned short smW[128 * 512];    // 131072 B, XOR-swizzled
    __shared__ __align__(16) unsigned short smX[8 * 1664];     // 26624 B, per-wave [16][104]

    // -------- zero-fill setup: this wave's row range + bitmap words in registers --------
    int chunk = (p < 4) ? 384 : 392;
    int pwr   = chunk >> 3;                    // rows per wave (48 or 49)
    int zr0   = blk * chunk + w * pwr;
    int zend  = min(blk * chunk + chunk, B_);
    int zn    = max(0, min(zr0 + pwr, zend) - zr0);
    unsigned long long zw0 = 0ull, zw1 = 0ull;
    int wi0 = zr0 >> 6;
    if (zn > 0) {
        zw0 = nb[p * 256 + wi0];
        zw1 = nb[p * 256 + ((zr0 + zn - 1) >> 6)];
    }
    // burst: zero rows [i0,i1) of this wave's range (fire-and-forget)
    auto zburst = [&](int i0, int i1) {
        i1 = min(i1, zn);
        float4 z = make_float4(0.f, 0.f, 0.f, 0.f);
        for (int i = i0; i < i1; ++i) {
            int zr = zr0 + i;
            unsigned long long wd = ((zr >> 6) == wi0) ? zw0 : zw1;
            if (!((wd >> (zr & 63)) & 1ull)) {
                size_t rb = ((size_t)p * B_ + zr) * 256 + l * 4;
                *(float4*)(out0 + rb) = z;
                *(float4*)(out1 + rb) = z;
                if (l == 0) out2[p * B_ + zr] = 0.f;
            }
        }
    };

    bool anyStage = (blk * 128) < cnt;   // block has at least one active compute wave
    int start = (blk * 8 + w) * 16;
    bool active = start < cnt;
    int nr = active ? min(16, cnt - start) : 0;
    int myrow = active ? lists[p * B_ + min(start + q, cnt - 1)] : 0;
    const float* Ab = mus     + (size_t)(p >> 1) * B_ * 256 + (size_t)myrow * 256 + g * 8;
    const float* Lb = logvars + (size_t)(p >> 1) * B_ * 256 + (size_t)myrow * 256 + g * 8;

    const unsigned short* w1p = w1t + (size_t)p * 65536;
    const unsigned short* w2p = w2f + (size_t)p * 9216;
    const unsigned short* w3p = w3f + (size_t)p * 49152;

    // -------- issue all 8 mus-chunk loads first (critical path), then zero burst 0 --------
    float4 ma[8], mb[8];
    if (active) {
#pragma unroll
        for (int k = 0; k < 8; ++k) {
            ma[k] = *(const float4*)(Ab + k * 32);
            mb[k] = *(const float4*)(Ab + k * 32 + 4);
        }
    }
    zburst(0, 6);

    if (anyStage) {
        {   // ---- stage full W1 into LDS, swizzled: block16 i' = i ^ (col&7) ----
            int c = t >> 2, qt = t & 3;
            const unsigned short* src = w1p + c * 512 + qt * 128;
            unsigned short* dstrow = smW + c * 512;
            int cx = c & 7;
#pragma unroll
            for (int jj = 0; jj < 16; ++jj) {
                int j = qt * 16 + jj;
                *(v8s*)(dstrow + (((j ^ cx)) << 3)) = *(const v8s*)(src + jj * 8);
            }
        }
        __syncthreads();    // the only block-wide barrier
    }

    unsigned short* mX = smX + w * 1664;
    float gb2p = gb2[p];

    if (active) {
        // ============ phase 1: acc1[8], K=512, zero barriers, fine zero-bursts woven in ============
        v4f acc1[8];
#pragma unroll
        for (int n = 0; n < 8; ++n) acc1[n] = (v4f){0.f, 0.f, 0.f, 0.f};

        int qx = q & 7;
        float4 la[8], lb[8];
#pragma unroll
        for (int kh = 0; kh < 4; ++kh) {
#pragma unroll
            for (int ki = 0; ki < 2; ++ki) {
                int kt = kh * 2 + ki;
                // issue logvars chunk kt (consumed in second half)
                la[kt] = *(const float4*)(Lb + kt * 32);
                lb[kt] = *(const float4*)(Lb + kt * 32 + 4);
                v8s a;
                a[0] = bfs(ma[kt].x); a[1] = bfs(ma[kt].y); a[2] = bfs(ma[kt].z); a[3] = bfs(ma[kt].w);
                a[4] = bfs(mb[kt].x); a[5] = bfs(mb[kt].y); a[6] = bfs(mb[kt].z); a[7] = bfs(mb[kt].w);
#pragma unroll
                for (int n = 0; n < 8; ++n) {
                    int i = kt * 4 + g;
                    v8s b = *(const v8s*)(smW + (n * 16 + q) * 512 + ((i ^ qx) << 3));
                    acc1[n] = __builtin_amdgcn_mfma_f32_16x16x32_bf16(b, a, acc1[n], 0, 0, 0);
                }
            }
            zburst(6 + 3 * kh, 9 + 3 * kh);          // 3 rows per 2 kt steps
        }
#pragma unroll
        for (int kh = 0; kh < 4; ++kh) {
#pragma unroll
            for (int ki = 0; ki < 2; ++ki) {
                int kt = kh * 2 + ki;
                v8s a;
                a[0] = bfs(la[kt].x); a[1] = bfs(la[kt].y); a[2] = bfs(la[kt].z); a[3] = bfs(la[kt].w);
                a[4] = bfs(lb[kt].x); a[5] = bfs(lb[kt].y); a[6] = bfs(lb[kt].z); a[7] = bfs(lb[kt].w);
#pragma unroll
                for (int n = 0; n < 8; ++n) {
                    int i = (kt + 8) * 4 + g;
                    v8s b = *(const v8s*)(smW + (n * 16 + q) * 512 + ((i ^ qx) << 3));
                    acc1[n] = __builtin_amdgcn_mfma_f32_16x16x32_bf16(b, a, acc1[n], 0, 0, 0);
                }
            }
            zburst(18 + 3 * kh, 21 + 3 * kh);
        }

        // ====== LN1 + gelu; lane (g,q) holds row q, cols {n*16+4g+j} ======
        {
            float vb[8][4];
#pragma unroll
            for (int n = 0; n < 8; ++n) {
                float4 bb = (n < 6) ? *(const float4*)(hb1 + p * 96 + n * 16 + 4 * g)
                                    : *(const float4*)(gb1 + p * 32 + (n - 6) * 16 + 4 * g);
                vb[n][0] = acc1[n][0] + bb.x; vb[n][1] = acc1[n][1] + bb.y;
                vb[n][2] = acc1[n][2] + bb.z; vb[n][3] = acc1[n][3] + bb.w;
            }
            float hs = 0.f;
#pragma unroll
            for (int n = 0; n < 6; ++n)
#pragma unroll
                for (int j = 0; j < 4; ++j) hs += vb[n][j];
            hs += __shfl_xor(hs, 16, 64); hs += __shfl_xor(hs, 32, 64);
            float mean = hs * (1.f / 96.f);
            float sq = 0.f;
#pragma unroll
            for (int n = 0; n < 6; ++n)
#pragma unroll
                for (int j = 0; j < 4; ++j) { float d = vb[n][j] - mean; sq += d * d; }
            sq += __shfl_xor(sq, 16, 64); sq += __shfl_xor(sq, 32, 64);
            float rs = rsqrtf(sq * (1.f / 96.f) + 1e-5f);
#pragma unroll
            for (int n = 0; n < 6; ++n) {
                float4 ga = *(const float4*)(hg1  + p * 96 + n * 16 + 4 * g);
                float4 be = *(const float4*)(hbe1 + p * 96 + n * 16 + 4 * g);
                v4s xo;
                xo[0] = bfs(gelu_f((vb[n][0] - mean) * rs * ga.x + be.x));
                xo[1] = bfs(gelu_f((vb[n][1] - mean) * rs * ga.y + be.y));
                xo[2] = bfs(gelu_f((vb[n][2] - mean) * rs * ga.z + be.z));
                xo[3] = bfs(gelu_f((vb[n][3] - mean) * rs * ga.w + be.w));
                *(v4s*)(mX + q * 104 + n * 16 + 4 * g) = xo;
            }
            // gate branch (cols 96..127 = frags n=6,7)
            float gs = 0.f;
#pragma unroll
            for (int n = 6; n < 8; ++n)
#pragma unroll
                for (int j = 0; j < 4; ++j) gs += vb[n][j];
            gs += __shfl_xor(gs, 16, 64); gs += __shfl_xor(gs, 32, 64);
            float mg = gs * (1.f / 32.f);
            float gq = 0.f;
#pragma unroll
            for (int n = 6; n < 8; ++n)
#pragma unroll
                for (int j = 0; j < 4; ++j) { float d = vb[n][j] - mg; gq += d * d; }
            gq += __shfl_xor(gq, 16, 64); gq += __shfl_xor(gq, 32, 64);
            float rg = rsqrtf(gq * (1.f / 32.f) + 1e-5f);
            float gv = 0.f;
#pragma unroll
            for (int n = 6; n < 8; ++n) {
                int cg = (n - 6) * 16 + 4 * g;
                float4 ga = *(const float4*)(gg1  + p * 32 + cg);
                float4 be = *(const float4*)(gbe1 + p * 32 + cg);
                float4 w2 = *(const float4*)(gw2  + p * 32 + cg);
                gv += gelu_f((vb[n][0] - mg) * rg * ga.x + be.x) * w2.x;
                gv += gelu_f((vb[n][1] - mg) * rg * ga.y + be.y) * w2.y;
                gv += gelu_f((vb[n][2] - mg) * rg * ga.z + be.z) * w2.z;
                gv += gelu_f((vb[n][3] - mg) * rg * ga.w + be.w) * w2.w;
            }
            gv += __shfl_xor(gv, 16, 64); gv += __shfl_xor(gv, 32, 64);
            if (g == 0 && q < nr)
                out2[p * B_ + myrow] = 1.f / (1.f + expf(-(gv + gb2p)));
        }
        zburst(30, 33);

        // ============ phase 2: X1 @ W2 (fragment-major, contiguous 1KB loads) ============
        {
            v4f acc2[6];
#pragma unroll
            for (int n = 0; n < 6; ++n) acc2[n] = (v4f){0.f, 0.f, 0.f, 0.f};
            int fo = q * 32 + g * 8;
#pragma unroll
            for (int kit = 0; kit < 3; ++kit) {
                v8s xa = *(const v8s*)(mX + q * 104 + kit * 32 + g * 8);
#pragma unroll
                for (int n = 0; n < 6; ++n) {
                    v8s wb = *(const v8s*)(w2p + (n * 3 + kit) * 512 + fo);
                    acc2[n] = __builtin_amdgcn_mfma_f32_16x16x32_bf16(wb, xa, acc2[n], 0, 0, 0);
                }
            }
            // LN2 + gelu -> X2 (same buffer)
            float vc[6][4];
#pragma unroll
            for (int n = 0; n < 6; ++n) {
                float4 bb = *(const float4*)(hb2 + p * 96 + n * 16 + 4 * g);
                vc[n][0] = acc2[n][0] + bb.x; vc[n][1] = acc2[n][1] + bb.y;
                vc[n][2] = acc2[n][2] + bb.z; vc[n][3] = acc2[n][3] + bb.w;
            }
            float hs = 0.f;
#pragma unroll
            for (int n = 0; n < 6; ++n)
#pragma unroll
                for (int j = 0; j < 4; ++j) hs += vc[n][j];
            hs += __shfl_xor(hs, 16, 64); hs += __shfl_xor(hs, 32, 64);
            float mean = hs * (1.f / 96.f);
            float sq = 0.f;
#pragma unroll
            for (int n = 0; n < 6; ++n)
#pragma unroll
                for (int j = 0; j < 4; ++j) { float d = vc[n][j] - mean; sq += d * d; }
            sq += __shfl_xor(sq, 16, 64); sq += __shfl_xor(sq, 32, 64);
            float rs = rsqrtf(sq * (1.f / 96.f) + 1e-5f);
#pragma unroll
            for (int n = 0; n < 6; ++n) {
                float4 ga = *(const float4*)(hg2  + p * 96 + n * 16 + 4 * g);
                float4 be = *(const float4*)(hbe2 + p * 96 + n * 16 + 4 * g);
                v4s xo;
                xo[0] = bfs(gelu_f((vc[n][0] - mean) * rs * ga.x + be.x));
                xo[1] = bfs(gelu_f((vc[n][1] - mean) * rs * ga.y + be.y));
                xo[2] = bfs(gelu_f((vc[n][2] - mean) * rs * ga.z + be.z));
                xo[3] = bfs(gelu_f((vc[n][3] - mean) * rs * ga.w + be.w));
                *(v4s*)(mX + q * 104 + n * 16 + 4 * g) = xo;
            }
        }
        zburst(33, 39);

        // ============ phase 3: X2 @ W3 (fragment-major), float4 stores + interleaved bursts ============
        {
            size_t base = ((size_t)(p * B_ + myrow)) * 256;
            int fo = q * 32 + g * 8;
#pragma unroll 1
            for (int pc = 0; pc < 4; ++pc) {
                v4f acc3[8];
#pragma unroll
                for (int n = 0; n < 8; ++n) acc3[n] = (v4f){0.f, 0.f, 0.f, 0.f};
#pragma unroll
                for (int kit = 0; kit < 3; ++kit) {
                    v8s xa = *(const v8s*)(mX + q * 104 + kit * 32 + g * 8);
#pragma unroll
                    for (int n = 0; n < 8; ++n) {
                        v8s wb = *(const v8s*)(w3p + ((pc * 8 + n) * 3 + kit) * 512 + fo);
                        acc3[n] = __builtin_amdgcn_mfma_f32_16x16x32_bf16(wb, xa, acc3[n], 0, 0, 0);
                    }
                }
#pragma unroll
                for (int n = 0; n < 8; ++n) {
                    int c = pc * 128 + n * 16 + 4 * g;
                    float4 bb = *(const float4*)(hb3 + p * 512 + c);
                    if (q < nr) {
                        float o0 = acc3[n][0] + bb.x, o1 = acc3[n][1] + bb.y;
                        float o2 = acc3[n][2] + bb.z, o3 = acc3[n][3] + bb.w;
                        if (pc < 2) {
                            *(float4*)(out0 + base + c) = make_float4(o0, o1, o2, o3);
                        } else {
                            o0 = fminf(fmaxf(o0, -6.f), 2.f); o1 = fminf(fmaxf(o1, -6.f), 2.f);
                            o2 = fminf(fmaxf(o2, -6.f), 2.f); o3 = fminf(fmaxf(o3, -6.f), 2.f);
                            *(float4*)(out1 + base + c - 256) = make_float4(o0, o1, o2, o3);
                        }
                    }
                }
                zburst(39 + pc * 2, 41 + pc * 2);
            }
        }
        zburst(47, pwr);
    } else {
        // inactive wave: finish remaining zero bursts immediately
        zburst(6, pwr);
    }
}

extern "C" void kernel_launch(void* const* d_in, const int* in_sizes, int n_in,
                              void* d_out, int out_size, void* d_ws, size_t ws_size,
                              hipStream_t stream)
{
    (void)in_sizes; (void)n_in; (void)out_size; (void)ws_size;

    const float* mus     = (const float*)d_in[0];
    const float* logvars = (const float*)d_in[1];
    const int*   mask    = (const int*)d_in[2];   // numpy bool -> int32 per harness
    const float* hw1  = (const float*)d_in[3];
    const float* hb1  = (const float*)d_in[4];
    const float* hg1  = (const float*)d_in[5];
    const float* hbe1 = (const float*)d_in[6];
    const float* hw2  = (const float*)d_in[7];
    const float* hb2  = (const float*)d_in[8];
    const float* hg2  = (const float*)d_in[9];
    const float* hbe2 = (const float*)d_in[10];
    const float* hw3  = (const float*)d_in[11];
    const float* hb3  = (const float*)d_in[12];
    const float* gw1  = (const float*)d_in[13];
    const float* gb1  = (const float*)d_in[14];
    const float* gg1  = (const float*)d_in[15];
    const float* gbe1 = (const float*)d_in[16];
    const float* gw2  = (const float*)d_in[17];
    const float* gb2  = (const float*)d_in[18];

    float* out0 = (float*)d_out;
    float* out1 = out0 + (size_t)NP * B_ * 256;
    float* out2 = out1 + (size_t)NP * B_ * 256;

    int* counts = (int*)d_ws;                                    // 16 ints
    int* lists  = counts + 16;                                   // NP*B_ ints
    unsigned short* w1t = (unsigned short*)(lists + NP * B_);    // NP*65536
    unsigned short* w2f = w1t + (size_t)NP * 65536;              // NP*9216
    unsigned short* w3f = w2f + (size_t)NP * 9216;               // NP*49152
    unsigned long long* nbm = (unsigned long long*)(w3f + (size_t)NP * 49152);  // NP*256

    hipMemsetAsync(d_ws, 0, 64, stream);
    k_pre<<<dim3(560), dim3(256), 0, stream>>>(
        mask, counts, lists, nbm, hw1, gw1, hw2, hw3, w1t, w2f, w3f);
    k_main<<<dim3(256), dim3(512), 0, stream>>>(
        mus, logvars, w1t, w2f, w3f,
        hb1, hg1, hbe1, hb2, hg2, hbe2, hb3,
        gb1, gg1, gbe1, gw2, gb2,
        counts, lists, nbm, out0, out1, out2);
}

// Round 19
// 91.715 us; speedup vs baseline: 1.0797x; 1.0319x over previous
//
#include <hip/hip_runtime.h>
#include <hip/hip_bf16.h>
#include <math.h>

#define B_ 16384
#define NP 6

typedef short v8s __attribute__((ext_vector_type(8)));
typedef short v4s __attribute__((ext_vector_type(4)));
typedef float v4f __attribute__((ext_vector_type(4)));

__device__ __forceinline__ float gelu_f(float x) {
    return 0.5f * x * (1.0f + erff(x * 0.7071067811865476f));
}
__device__ __forceinline__ unsigned short f2bf(float f) {
    union { float f; unsigned u; } x; x.f = f;
    unsigned r = x.u + 0x7FFFu + ((x.u >> 16) & 1u);
    return (unsigned short)(r >> 16);
}
__device__ __forceinline__ short bfs(float f) {   // HW RTNE cvt
    union { __hip_bfloat16 h; unsigned short u; } cv;
    cv.h = __float2bfloat16(f);
    return (short)cv.u;
}

// ---------------- kernel 1: fused {counts+lists+bitmap} and {weights->bf16 repack} ----------------
// blocks 0..47: mask compaction; blocks 48..559: weight conversion
__global__ __launch_bounds__(256) void k_pre(
    const int* __restrict__ mask, int* __restrict__ counts,
    int* __restrict__ lists, unsigned long long* __restrict__ nb,
    const float* __restrict__ hw1, const float* __restrict__ gw1,
    const float* __restrict__ hw2, const float* __restrict__ hw3,
    unsigned short* __restrict__ w1t, unsigned short* __restrict__ w2f,
    unsigned short* __restrict__ w3f)
{
    int t = threadIdx.x;
    if (blockIdx.x < 48) {
        int p   = blockIdx.x >> 3;
        int seg = blockIdx.x & 7;
        int src = p >> 1;                        // 0,0,1,1,2,2
        int tgt = (0x102021 >> (p * 4)) & 0xF;   // 1,2,0,2,0,1
        int lane = t & 63;
        for (int it = 0; it < 8; ++it) {
            int b = seg * 2048 + it * 256 + t;
            int needs = (mask[b * 3 + src] != 0) && (mask[b * 3 + tgt] == 0);
            unsigned long long bal = __ballot(needs);
            int total = __popcll(bal);
            int base = 0;
            if (lane == 0) {
                nb[p * 256 + (b >> 6)] = bal;
                if (total) base = atomicAdd(&counts[p], total);
            }
            base = __shfl(base, 0, 64);
            if (needs) {
                int prefix = __popcll(bal & ((1ull << lane) - 1ull));
                lists[p * B_ + base + prefix] = b;
            }
        }
        return;
    }
    const int T1 = NP * 65536, T2 = NP * 9216, T3 = NP * 49152;
    for (int i = (blockIdx.x - 48) * 256 + t; i < T1 + T2 + T3; i += 512 * 256) {
        if (i < T1) {
            int p = i >> 16, rem = i & 65535, c = rem >> 9, k = rem & 511;
            float v = (c < 96) ? hw1[p * 49152 + k * 96 + c] : gw1[p * 16384 + k * 32 + (c - 96)];
            w1t[i] = f2bf(v);
        } else if (i < T1 + T2) {
            // w2f: ((p*18 + f)*64 + q*4 + g)*8 + j ; f = n*3+kit
            int j2 = i - T1, p = j2 / 9216, rem = j2 % 9216;
            int f = rem >> 9, within = rem & 511;
            int qg = within >> 3, j = within & 7;
            int q = qg >> 2, g = qg & 3;
            int k = (f % 3) * 32 + g * 8 + j;
            int col = (f / 3) * 16 + q;
            w2f[j2] = f2bf(hw2[p * 9216 + k * 96 + col]);
        } else {
            // w3f: ((p*96 + f)*64 + q*4 + g)*8 + j ; f = (pc*8+n)*3+kit
            int j3 = i - T1 - T2, p = j3 / 49152, rem = j3 % 49152;
            int f = rem >> 9, within = rem & 511;
            int qg = within >> 3, j = within & 7;
            int q = qg >> 2, g = qg & 3;
            int k = (f % 3) * 32 + g * 8 + j;
            int col = (f / 3) * 16 + q;
            w3f[j3] = f2bf(hw3[p * 49152 + k * 512 + col]);
        }
    }
}

// ---------------- kernel 2: burst-interleaved zero-fill + persistent W1-in-LDS MFMA MLP ----------------
// 256 blocks x 512 threads (8 waves). One block per CU.
__global__ __launch_bounds__(512, 2) void k_main(
    const float* __restrict__ mus, const float* __restrict__ logvars,
    const unsigned short* __restrict__ w1t, const unsigned short* __restrict__ w2f,
    const unsigned short* __restrict__ w3f,
    const float* __restrict__ hb1, const float* __restrict__ hg1, const float* __restrict__ hbe1,
    const float* __restrict__ hb2, const float* __restrict__ hg2, const float* __restrict__ hbe2,
    const float* __restrict__ hb3,
    const float* __restrict__ gb1, const float* __restrict__ gg1, const float* __restrict__ gbe1,
    const float* __restrict__ gw2, const float* __restrict__ gb2,
    const int* __restrict__ counts, const int* __restrict__ lists,
    const unsigned long long* __restrict__ nb,
    float* __restrict__ out0, float* __restrict__ out1, float* __restrict__ out2)
{
    int cb = blockIdx.x;                 // 0..255
    int p  = cb % 6, blk = cb / 6;       // p<4: blk 0..42 ; p>=4: blk 0..41
    int t  = threadIdx.x;
    int w  = t >> 6, l = t & 63, g = l >> 4, q = l & 15;
    int cnt = counts[p];

    __shared__ __align__(16) unsigned short smW[128 * 512];    // 131072 B, XOR-swizzled
    __shared__ __align__(16) unsigned short smX[8 * 1664];     // 26624 B, per-wave [16][104]

    // -------- zero-fill setup: this wave's row range + bitmap words in registers --------
    int chunk = (p < 4) ? 384 : 392;
    int pwr   = chunk >> 3;                    // rows per wave (48 or 49)
    int zr0   = blk * chunk + w * pwr;
    int zend  = min(blk * chunk + chunk, B_);
    int zn    = max(0, min(zr0 + pwr, zend) - zr0);
    unsigned long long zw0 = 0ull, zw1 = 0ull;
    int wi0 = zr0 >> 6;
    if (zn > 0) {
        zw0 = nb[p * 256 + wi0];
        zw1 = nb[p * 256 + ((zr0 + zn - 1) >> 6)];
    }
    // burst: zero rows [i0,i1) of this wave's range (fire-and-forget)
    auto zburst = [&](int i0, int i1) {
        i1 = min(i1, zn);
        float4 z = make_float4(0.f, 0.f, 0.f, 0.f);
        for (int i = i0; i < i1; ++i) {
            int zr = zr0 + i;
            unsigned long long wd = ((zr >> 6) == wi0) ? zw0 : zw1;
            if (!((wd >> (zr & 63)) & 1ull)) {
                size_t rb = ((size_t)p * B_ + zr) * 256 + l * 4;
                *(float4*)(out0 + rb) = z;
                *(float4*)(out1 + rb) = z;
                if (l == 0) out2[p * B_ + zr] = 0.f;
            }
        }
    };

    bool anyStage = (blk * 128) < cnt;   // block has at least one active compute wave
    int start = (blk * 8 + w) * 16;
    bool active = start < cnt;
    int nr = active ? min(16, cnt - start) : 0;
    int myrow = active ? lists[p * B_ + min(start + q, cnt - 1)] : 0;
    const float* Ab = mus     + (size_t)(p >> 1) * B_ * 256 + (size_t)myrow * 256 + g * 8;
    const float* Lb = logvars + (size_t)(p >> 1) * B_ * 256 + (size_t)myrow * 256 + g * 8;

    const unsigned short* w1p = w1t + (size_t)p * 65536;
    const unsigned short* w2p = w2f + (size_t)p * 9216;
    const unsigned short* w3p = w3f + (size_t)p * 49152;

    // -------- issue all 8 mus-chunk loads first (critical path), then zero burst 0 --------
    float4 ma[8], mb[8];
    if (active) {
#pragma unroll
        for (int k = 0; k < 8; ++k) {
            ma[k] = *(const float4*)(Ab + k * 32);
            mb[k] = *(const float4*)(Ab + k * 32 + 4);
        }
    }
    zburst(0, 12);

    if (anyStage) {
        {   // ---- stage full W1 into LDS, swizzled: block16 i' = i ^ (col&7) ----
            int c = t >> 2, qt = t & 3;
            const unsigned short* src = w1p + c * 512 + qt * 128;
            unsigned short* dstrow = smW + c * 512;
            int cx = c & 7;
#pragma unroll
            for (int jj = 0; jj < 16; ++jj) {
                int j = qt * 16 + jj;
                *(v8s*)(dstrow + (((j ^ cx)) << 3)) = *(const v8s*)(src + jj * 8);
            }
        }
        __syncthreads();    // the only block-wide barrier
    }

    unsigned short* mX = smX + w * 1664;
    float gb2p = gb2[p];

    if (active) {
        // ============ phase 1: acc1[8], K=512, zero barriers ============
        v4f acc1[8];
#pragma unroll
        for (int n = 0; n < 8; ++n) acc1[n] = (v4f){0.f, 0.f, 0.f, 0.f};

        int qx = q & 7;
        float4 la[8], lb[8];
#pragma unroll
        for (int kt = 0; kt < 8; ++kt) {
            // issue logvars chunk kt (consumed in second half)
            la[kt] = *(const float4*)(Lb + kt * 32);
            lb[kt] = *(const float4*)(Lb + kt * 32 + 4);
            v8s a;
            a[0] = bfs(ma[kt].x); a[1] = bfs(ma[kt].y); a[2] = bfs(ma[kt].z); a[3] = bfs(ma[kt].w);
            a[4] = bfs(mb[kt].x); a[5] = bfs(mb[kt].y); a[6] = bfs(mb[kt].z); a[7] = bfs(mb[kt].w);
#pragma unroll
            for (int n = 0; n < 8; ++n) {
                int i = kt * 4 + g;
                v8s b = *(const v8s*)(smW + (n * 16 + q) * 512 + ((i ^ qx) << 3));
                acc1[n] = __builtin_amdgcn_mfma_f32_16x16x32_bf16(b, a, acc1[n], 0, 0, 0);
            }
        }
        zburst(12, 24);   // drain overlaps logvars-half MFMAs
#pragma unroll
        for (int kt = 0; kt < 8; ++kt) {
            v8s a;
            a[0] = bfs(la[kt].x); a[1] = bfs(la[kt].y); a[2] = bfs(la[kt].z); a[3] = bfs(la[kt].w);
            a[4] = bfs(lb[kt].x); a[5] = bfs(lb[kt].y); a[6] = bfs(lb[kt].z); a[7] = bfs(lb[kt].w);
#pragma unroll
            for (int n = 0; n < 8; ++n) {
                int i = (kt + 8) * 4 + g;
                v8s b = *(const v8s*)(smW + (n * 16 + q) * 512 + ((i ^ qx) << 3));
                acc1[n] = __builtin_amdgcn_mfma_f32_16x16x32_bf16(b, a, acc1[n], 0, 0, 0);
            }
        }

        // ====== LN1 + gelu; lane (g,q) holds row q, cols {n*16+4g+j} ======
        {
            float vb[8][4];
#pragma unroll
            for (int n = 0; n < 8; ++n) {
                float4 bb = (n < 6) ? *(const float4*)(hb1 + p * 96 + n * 16 + 4 * g)
                                    : *(const float4*)(gb1 + p * 32 + (n - 6) * 16 + 4 * g);
                vb[n][0] = acc1[n][0] + bb.x; vb[n][1] = acc1[n][1] + bb.y;
                vb[n][2] = acc1[n][2] + bb.z; vb[n][3] = acc1[n][3] + bb.w;
            }
            float hs = 0.f;
#pragma unroll
            for (int n = 0; n < 6; ++n)
#pragma unroll
                for (int j = 0; j < 4; ++j) hs += vb[n][j];
            hs += __shfl_xor(hs, 16, 64); hs += __shfl_xor(hs, 32, 64);
            float mean = hs * (1.f / 96.f);
            float sq = 0.f;
#pragma unroll
            for (int n = 0; n < 6; ++n)
#pragma unroll
                for (int j = 0; j < 4; ++j) { float d = vb[n][j] - mean; sq += d * d; }
            sq += __shfl_xor(sq, 16, 64); sq += __shfl_xor(sq, 32, 64);
            float rs = rsqrtf(sq * (1.f / 96.f) + 1e-5f);
#pragma unroll
            for (int n = 0; n < 6; ++n) {
                float4 ga = *(const float4*)(hg1  + p * 96 + n * 16 + 4 * g);
                float4 be = *(const float4*)(hbe1 + p * 96 + n * 16 + 4 * g);
                v4s xo;
                xo[0] = bfs(gelu_f((vb[n][0] - mean) * rs * ga.x + be.x));
                xo[1] = bfs(gelu_f((vb[n][1] - mean) * rs * ga.y + be.y));
                xo[2] = bfs(gelu_f((vb[n][2] - mean) * rs * ga.z + be.z));
                xo[3] = bfs(gelu_f((vb[n][3] - mean) * rs * ga.w + be.w));
                *(v4s*)(mX + q * 104 + n * 16 + 4 * g) = xo;
            }
            // gate branch (cols 96..127 = frags n=6,7)
            float gs = 0.f;
#pragma unroll
            for (int n = 6; n < 8; ++n)
#pragma unroll
                for (int j = 0; j < 4; ++j) gs += vb[n][j];
            gs += __shfl_xor(gs, 16, 64); gs += __shfl_xor(gs, 32, 64);
            float mg = gs * (1.f / 32.f);
            float gq = 0.f;
#pragma unroll
            for (int n = 6; n < 8; ++n)
#pragma unroll
                for (int j = 0; j < 4; ++j) { float d = vb[n][j] - mg; gq += d * d; }
            gq += __shfl_xor(gq, 16, 64); gq += __shfl_xor(gq, 32, 64);
            float rg = rsqrtf(gq * (1.f / 32.f) + 1e-5f);
            float gv = 0.f;
#pragma unroll
            for (int n = 6; n < 8; ++n) {
                int cg = (n - 6) * 16 + 4 * g;
                float4 ga = *(const float4*)(gg1  + p * 32 + cg);
                float4 be = *(const float4*)(gbe1 + p * 32 + cg);
                float4 w2 = *(const float4*)(gw2  + p * 32 + cg);
                gv += gelu_f((vb[n][0] - mg) * rg * ga.x + be.x) * w2.x;
                gv += gelu_f((vb[n][1] - mg) * rg * ga.y + be.y) * w2.y;
                gv += gelu_f((vb[n][2] - mg) * rg * ga.z + be.z) * w2.z;
                gv += gelu_f((vb[n][3] - mg) * rg * ga.w + be.w) * w2.w;
            }
            gv += __shfl_xor(gv, 16, 64); gv += __shfl_xor(gv, 32, 64);
            if (g == 0 && q < nr)
                out2[p * B_ + myrow] = 1.f / (1.f + expf(-(gv + gb2p)));
        }

        // ============ phase 2: X1 @ W2 (fragment-major, contiguous 1KB loads) ============
        {
            v4f acc2[6];
#pragma unroll
            for (int n = 0; n < 6; ++n) acc2[n] = (v4f){0.f, 0.f, 0.f, 0.f};
            int fo = q * 32 + g * 8;
#pragma unroll
            for (int kit = 0; kit < 3; ++kit) {
                v8s xa = *(const v8s*)(mX + q * 104 + kit * 32 + g * 8);
#pragma unroll
                for (int n = 0; n < 6; ++n) {
                    v8s wb = *(const v8s*)(w2p + (n * 3 + kit) * 512 + fo);
                    acc2[n] = __builtin_amdgcn_mfma_f32_16x16x32_bf16(wb, xa, acc2[n], 0, 0, 0);
                }
            }
            // LN2 + gelu -> X2 (same buffer)
            float vc[6][4];
#pragma unroll
            for (int n = 0; n < 6; ++n) {
                float4 bb = *(const float4*)(hb2 + p * 96 + n * 16 + 4 * g);
                vc[n][0] = acc2[n][0] + bb.x; vc[n][1] = acc2[n][1] + bb.y;
                vc[n][2] = acc2[n][2] + bb.z; vc[n][3] = acc2[n][3] + bb.w;
            }
            float hs = 0.f;
#pragma unroll
            for (int n = 0; n < 6; ++n)
#pragma unroll
                for (int j = 0; j < 4; ++j) hs += vc[n][j];
            hs += __shfl_xor(hs, 16, 64); hs += __shfl_xor(hs, 32, 64);
            float mean = hs * (1.f / 96.f);
            float sq = 0.f;
#pragma unroll
            for (int n = 0; n < 6; ++n)
#pragma unroll
                for (int j = 0; j < 4; ++j) { float d = vc[n][j] - mean; sq += d * d; }
            sq += __shfl_xor(sq, 16, 64); sq += __shfl_xor(sq, 32, 64);
            float rs = rsqrtf(sq * (1.f / 96.f) + 1e-5f);
#pragma unroll
            for (int n = 0; n < 6; ++n) {
                float4 ga = *(const float4*)(hg2  + p * 96 + n * 16 + 4 * g);
                float4 be = *(const float4*)(hbe2 + p * 96 + n * 16 + 4 * g);
                v4s xo;
                xo[0] = bfs(gelu_f((vc[n][0] - mean) * rs * ga.x + be.x));
                xo[1] = bfs(gelu_f((vc[n][1] - mean) * rs * ga.y + be.y));
                xo[2] = bfs(gelu_f((vc[n][2] - mean) * rs * ga.z + be.z));
                xo[3] = bfs(gelu_f((vc[n][3] - mean) * rs * ga.w + be.w));
                *(v4s*)(mX + q * 104 + n * 16 + 4 * g) = xo;
            }
        }
        zburst(24, pwr);   // all remaining zeros issued here; drain overlaps phase 3

        // ============ phase 3: X2 @ W3 (fragment-major), float4 stores (live rows only) ============
        {
            size_t base = ((size_t)(p * B_ + myrow)) * 256;
            int fo = q * 32 + g * 8;
#pragma unroll 1
            for (int pc = 0; pc < 4; ++pc) {
                v4f acc3[8];
#pragma unroll
                for (int n = 0; n < 8; ++n) acc3[n] = (v4f){0.f, 0.f, 0.f, 0.f};
#pragma unroll
                for (int kit = 0; kit < 3; ++kit) {
                    v8s xa = *(const v8s*)(mX + q * 104 + kit * 32 + g * 8);
#pragma unroll
                    for (int n = 0; n < 8; ++n) {
                        v8s wb = *(const v8s*)(w3p + ((pc * 8 + n) * 3 + kit) * 512 + fo);
                        acc3[n] = __builtin_amdgcn_mfma_f32_16x16x32_bf16(wb, xa, acc3[n], 0, 0, 0);
                    }
                }
#pragma unroll
                for (int n = 0; n < 8; ++n) {
                    int c = pc * 128 + n * 16 + 4 * g;
                    float4 bb = *(const float4*)(hb3 + p * 512 + c);
                    if (q < nr) {
                        float o0 = acc3[n][0] + bb.x, o1 = acc3[n][1] + bb.y;
                        float o2 = acc3[n][2] + bb.z, o3 = acc3[n][3] + bb.w;
                        if (pc < 2) {
                            *(float4*)(out0 + base + c) = make_float4(o0, o1, o2, o3);
                        } else {
                            o0 = fminf(fmaxf(o0, -6.f), 2.f); o1 = fminf(fmaxf(o1, -6.f), 2.f);
                            o2 = fminf(fmaxf(o2, -6.f), 2.f); o3 = fminf(fmaxf(o3, -6.f), 2.f);
                            *(float4*)(out1 + base + c - 256) = make_float4(o0, o1, o2, o3);
                        }
                    }
                }
            }
        }
    } else {
        // inactive wave: finish remaining zero bursts immediately
        zburst(12, pwr);
    }
}

extern "C" void kernel_launch(void* const* d_in, const int* in_sizes, int n_in,
                              void* d_out, int out_size, void* d_ws, size_t ws_size,
                              hipStream_t stream)
{
    (void)in_sizes; (void)n_in; (void)out_size; (void)ws_size;

    const float* mus     = (const float*)d_in[0];
    const float* logvars = (const float*)d_in[1];
    const int*   mask    = (const int*)d_in[2];   // numpy bool -> int32 per harness
    const float* hw1  = (const float*)d_in[3];
    const float* hb1  = (const float*)d_in[4];
    const float* hg1  = (const float*)d_in[5];
    const float* hbe1 = (const float*)d_in[6];
    const float* hw2  = (const float*)d_in[7];
    const float* hb2  = (const float*)d_in[8];
    const float* hg2  = (const float*)d_in[9];
    const float* hbe2 = (const float*)d_in[10];
    const float* hw3  = (const float*)d_in[11];
    const float* hb3  = (const float*)d_in[12];
    const float* gw1  = (const float*)d_in[13];
    const float* gb1  = (const float*)d_in[14];
    const float* gg1  = (const float*)d_in[15];
    const float* gbe1 = (const float*)d_in[16];
    const float* gw2  = (const float*)d_in[17];
    const float* gb2  = (const float*)d_in[18];

    float* out0 = (float*)d_out;
    float* out1 = out0 + (size_t)NP * B_ * 256;
    float* out2 = out1 + (size_t)NP * B_ * 256;

    int* counts = (int*)d_ws;                                    // 16 ints
    int* lists  = counts + 16;                                   // NP*B_ ints
    unsigned short* w1t = (unsigned short*)(lists + NP * B_);    // NP*65536
    unsigned short* w2f = w1t + (size_t)NP * 65536;              // NP*9216
    unsigned short* w3f = w2f + (size_t)NP * 9216;               // NP*49152
    unsigned long long* nbm = (unsigned long long*)(w3f + (size_t)NP * 49152);  // NP*256

    hipMemsetAsync(d_ws, 0, 64, stream);
    k_pre<<<dim3(560), dim3(256), 0, stream>>>(
        mask, counts, lists, nbm, hw1, gw1, hw2, hw3, w1t, w2f, w3f);
    k_main<<<dim3(256), dim3(512), 0, stream>>>(
        mus, logvars, w1t, w2f, w3f,
        hb1, hg1, hbe1, hb2, hg2, hbe2, hb3,
        gb1, gg1, gbe1, gw2, gb2,
        counts, lists, nbm, out0, out1, out2);
}